// Round 1
// baseline (10248.343 us; speedup 1.0000x reference)
//
#include <hip/hip_runtime.h>
#include <hip/hip_bf16.h>
#include <stdint.h>

#define E_SZ 300
#define H_SZ 512
#define O_SZ 5
#define B_SZ 256
#define T_SZ 200
#define PAD_IDX 1

#define KH 512
#define KE 320            // padded e-width (300 -> 320)
#define KTOT 832          // 512 + 320
#define XS_W 812          // E + H, original weight row width

#define NRG 8             // row groups (batch split)
#define ROWS 32           // rows per WG
#define NSPLIT 32         // n splits
#define NW 16             // n columns per WG (per gate)
#define WGS (NRG * NSPLIT)      // 256 workgroups
#define GROUP_WGS NSPLIT        // WGs per row-group barrier

typedef __bf16 bf16x8 __attribute__((ext_vector_type(8)));
typedef float  f32x4  __attribute__((ext_vector_type(4)));

__device__ __forceinline__ float fsig(float x) { return 1.0f / (1.0f + __expf(-x)); }
__device__ __forceinline__ float ftanh_(float x) {
    float ax = fabsf(x);
    float e  = __expf(-2.0f * ax);
    float r  = (1.0f - e) / (1.0f + e);
    return x < 0.0f ? -r : r;
}

// ---------------- setup kernels ----------------

// Pack Wi/Wf/Wg/Wo ([512][812] f32) into Wp[2048][832] bf16.
// k<512: h-part (W[:, :512]); k in [512,812+..): e-part W[:, 512+e], zero-padded to 832.
__global__ void k_pack(const float* __restrict__ Wi, const float* __restrict__ Wf,
                       const float* __restrict__ Wg, const float* __restrict__ Wo,
                       __hip_bfloat16* __restrict__ Wp) {
    int idx = blockIdx.x * blockDim.x + threadIdx.x;
    int total = 4 * H_SZ * KTOT;
    for (int i = idx; i < total; i += gridDim.x * blockDim.x) {
        int k  = i % KTOT;
        int gn = i / KTOT;
        int g = gn >> 9, n = gn & 511;
        const float* W = (g == 0) ? Wi : (g == 1) ? Wf : (g == 2) ? Wg : Wo;
        float v = 0.0f;
        if (k < KH) v = W[n * XS_W + k];
        else { int e = k - KH; if (e < E_SZ) v = W[n * XS_W + KH + e]; }
        Wp[(size_t)gn * KTOT + k] = __float2bfloat16(v);
    }
}

// Gather embeddings: ebf[t][b][0..319] bf16 (zero-padded past 300).
__global__ void k_gather(const int* __restrict__ x, const float* __restrict__ embed,
                         __hip_bfloat16* __restrict__ ebf) {
    int cid = blockIdx.x * blockDim.x + threadIdx.x;   // chunk of 8 elems
    const int nch = T_SZ * B_SZ * (KE / 8);            // 2,048,000
    if (cid >= nch) return;
    int ch = cid % (KE / 8);
    int tb = cid / (KE / 8);
    int b = tb % B_SZ;
    int t = tb / B_SZ;
    int row = x[b * T_SZ + t];
    const float* er = embed + (size_t)row * E_SZ;
    __hip_bfloat16 v[8];
    int e0 = ch * 8;
#pragma unroll
    for (int j = 0; j < 8; ++j) {
        int e = e0 + j;
        float f = (e < E_SZ) ? er[e] : 0.0f;
        v[j] = __float2bfloat16(f);
    }
    *reinterpret_cast<ulonglong2*>(ebf + ((size_t)t * B_SZ + b) * KE + e0) =
        *reinterpret_cast<const ulonglong2*>(v);
}

// Zero h buffers / final_h / counters; compute capture step per batch row.
__global__ void k_misc(const int* __restrict__ x, __hip_bfloat16* __restrict__ hbuf,
                       float* __restrict__ final_h, int* __restrict__ tcap,
                       int* __restrict__ cnt) {
    int tid = blockIdx.x * blockDim.x + threadIdx.x;
    int nthr = gridDim.x * blockDim.x;
    for (int i = tid; i < 2 * B_SZ * H_SZ / 2; i += nthr)
        reinterpret_cast<uint32_t*>(hbuf)[i] = 0u;
    for (int i = tid; i < B_SZ * H_SZ; i += nthr)
        final_h[i] = 0.0f;
    if (blockIdx.x == 0 && threadIdx.x < NRG) cnt[threadIdx.x] = 0;
    if (tid < B_SZ) {
        int len = 0;
        for (int t = 0; t < T_SZ; ++t) len += (x[tid * T_SZ + t] != PAD_IDX);
        int tf = (len > 0) ? (len - 1) : 0;
        tcap[tid] = (x[tid * T_SZ + tf] == PAD_IDX) ? -1 : tf;
    }
}

// ---------------- recurrent cooperative kernel ----------------
// Grid: 256 WGs x 256 threads. WG (rg, ns): rows rg*32..+31, n-cols ns*16..+15 (x4 gates).
// Wave w computes gate w: 32 rows x 16 cols, K=832 via mfma_f32_16x16x32_bf16.
__global__ void __launch_bounds__(256, 1)
k_lstm(const __hip_bfloat16* __restrict__ Wp, const __hip_bfloat16* __restrict__ ebf,
       const float* __restrict__ bi, const float* __restrict__ bfv,
       const float* __restrict__ bg, const float* __restrict__ bo,
       __hip_bfloat16* __restrict__ hbuf, float* __restrict__ final_h,
       const int* __restrict__ tcap, int* __restrict__ cnt) {
    const int wg   = blockIdx.x;
    const int rg   = wg >> 5;        // / NSPLIT
    const int ns   = wg & 31;
    const int b0   = rg * ROWS;
    const int n0   = ns * NW;
    const int tid  = threadIdx.x;
    const int wave = tid >> 6;       // == gate index
    const int lane = tid & 63;
    const int l15  = lane & 15;
    const int l4   = lane >> 4;

    __shared__ float pre_lds[4][ROWS][NW];  // 8 KB gate pre-activations
    __shared__ float c_lds[ROWS][NW];       // 2 KB cell state (f32, persistent)

    for (int i = tid; i < ROWS * NW; i += 256) ((float*)c_lds)[i] = 0.0f;

    // B-fragment base: row gn = wave*512 + n0 + l15, k-offset l4*8
    const __hip_bfloat16* wB =
        Wp + ((size_t)(wave * H_SZ + n0 + l15)) * KTOT + l4 * 8;

    // per-thread elementwise constants (2 outputs per thread)
    const int idx0 = tid, idx1 = tid + 256;
    const int r0 = idx0 >> 4, c0 = idx0 & 15;
    const int r1 = idx1 >> 4, c1 = idx1 & 15;
    const int nn0 = n0 + c0, nn1 = n0 + c1;
    const int bb0 = b0 + r0, bb1 = b0 + r1;
    const float bi0 = bi[nn0], bf0 = bfv[nn0], bg0 = bg[nn0], bo0 = bo[nn0];
    const float bi1 = bi[nn1], bf1 = bfv[nn1], bg1 = bg[nn1], bo1 = bo[nn1];
    const int tc0 = tcap[bb0], tc1 = tcap[bb1];

    __syncthreads();

    int cur = 0;
    for (int t = 0; t < T_SZ; ++t) {
        f32x4 acc0 = {0.f, 0.f, 0.f, 0.f};
        f32x4 acc1 = {0.f, 0.f, 0.f, 0.f};
        const __hip_bfloat16* hb = hbuf + (size_t)cur * B_SZ * H_SZ;
        const __hip_bfloat16* arow0 = hb + (size_t)(b0 + l15) * H_SZ + l4 * 8;
        const __hip_bfloat16* arow1 = hb + (size_t)(b0 + 16 + l15) * H_SZ + l4 * 8;
#pragma unroll
        for (int kk = 0; kk < 16; ++kk) {   // h-part of K
            bf16x8 a0 = *reinterpret_cast<const bf16x8*>(arow0 + kk * 32);
            bf16x8 a1 = *reinterpret_cast<const bf16x8*>(arow1 + kk * 32);
            bf16x8 bw = *reinterpret_cast<const bf16x8*>(wB + kk * 32);
            acc0 = __builtin_amdgcn_mfma_f32_16x16x32_bf16(a0, bw, acc0, 0, 0, 0);
            acc1 = __builtin_amdgcn_mfma_f32_16x16x32_bf16(a1, bw, acc1, 0, 0, 0);
        }
        const __hip_bfloat16* eb = ebf + ((size_t)t * B_SZ) * KE;
        const __hip_bfloat16* erow0 = eb + (size_t)(b0 + l15) * KE + l4 * 8;
        const __hip_bfloat16* erow1 = eb + (size_t)(b0 + 16 + l15) * KE + l4 * 8;
#pragma unroll
        for (int kk = 0; kk < 10; ++kk) {   // e-part of K
            bf16x8 a0 = *reinterpret_cast<const bf16x8*>(erow0 + kk * 32);
            bf16x8 a1 = *reinterpret_cast<const bf16x8*>(erow1 + kk * 32);
            bf16x8 bw = *reinterpret_cast<const bf16x8*>(wB + (16 + kk) * 32);
            acc0 = __builtin_amdgcn_mfma_f32_16x16x32_bf16(a0, bw, acc0, 0, 0, 0);
            acc1 = __builtin_amdgcn_mfma_f32_16x16x32_bf16(a1, bw, acc1, 0, 0, 0);
        }
        // scatter pre-activations to LDS (C/D layout: row=(lane>>4)*4+j, col=lane&15)
#pragma unroll
        for (int j = 0; j < 4; ++j) {
            pre_lds[wave][l4 * 4 + j][l15]      = acc0[j];
            pre_lds[wave][16 + l4 * 4 + j][l15] = acc1[j];
        }
        __syncthreads();

        __hip_bfloat16* hn = hbuf + (size_t)(cur ^ 1) * B_SZ * H_SZ;
        {
            float pi = pre_lds[0][r0][c0] + bi0;
            float pf = pre_lds[1][r0][c0] + bf0;
            float pg = pre_lds[2][r0][c0] + bg0;
            float po = pre_lds[3][r0][c0] + bo0;
            float ig = fsig(pi), fg = fsig(pf), gg = ftanh_(pg), og = fsig(po);
            float cn = fg * c_lds[r0][c0] + ig * gg;
            c_lds[r0][c0] = cn;
            float hv = ftanh_(cn) * og;
            hn[(size_t)bb0 * H_SZ + nn0] = __float2bfloat16(hv);
            if (t == tc0) final_h[(size_t)bb0 * H_SZ + nn0] = hv;
        }
        {
            float pi = pre_lds[0][r1][c1] + bi1;
            float pf = pre_lds[1][r1][c1] + bf1;
            float pg = pre_lds[2][r1][c1] + bg1;
            float po = pre_lds[3][r1][c1] + bo1;
            float ig = fsig(pi), fg = fsig(pf), gg = ftanh_(pg), og = fsig(po);
            float cn = fg * c_lds[r1][c1] + ig * gg;
            c_lds[r1][c1] = cn;
            float hv = ftanh_(cn) * og;
            hn[(size_t)bb1 * H_SZ + nn1] = __float2bfloat16(hv);
            if (t == tc1) final_h[(size_t)bb1 * H_SZ + nn1] = hv;
        }

        // row-group barrier (release h writes, acquire others')
        __syncthreads();
        __threadfence();
        if (tid == 0) {
            atomicAdd(&cnt[rg], 1);
            const int target = GROUP_WGS * (t + 1);
            while (__hip_atomic_load(&cnt[rg], __ATOMIC_RELAXED,
                                     __HIP_MEMORY_SCOPE_AGENT) < target) {
                __builtin_amdgcn_s_sleep(1);
            }
        }
        __syncthreads();
        __threadfence();
        cur ^= 1;
    }
}

// ---------------- output head ----------------
__global__ void k_out(const float* __restrict__ fin, const float* __restrict__ Wout,
                      const float* __restrict__ bout, float* __restrict__ out) {
    int b = blockIdx.x;
    int lane = threadIdx.x;  // 64
    float s0 = 0, s1 = 0, s2 = 0, s3 = 0, s4 = 0;
    const float* fr = fin + (size_t)b * H_SZ;
    for (int n = lane; n < H_SZ; n += 64) {
        float h = fr[n];
        s0 += h * Wout[0 * H_SZ + n];
        s1 += h * Wout[1 * H_SZ + n];
        s2 += h * Wout[2 * H_SZ + n];
        s3 += h * Wout[3 * H_SZ + n];
        s4 += h * Wout[4 * H_SZ + n];
    }
#pragma unroll
    for (int off = 32; off >= 1; off >>= 1) {
        s0 += __shfl_down(s0, off);
        s1 += __shfl_down(s1, off);
        s2 += __shfl_down(s2, off);
        s3 += __shfl_down(s3, off);
        s4 += __shfl_down(s4, off);
    }
    if (lane == 0) {
        out[b * O_SZ + 0] = s0 + bout[0];
        out[b * O_SZ + 1] = s1 + bout[1];
        out[b * O_SZ + 2] = s2 + bout[2];
        out[b * O_SZ + 3] = s3 + bout[3];
        out[b * O_SZ + 4] = s4 + bout[4];
    }
}

// ---------------- launch ----------------
extern "C" void kernel_launch(void* const* d_in, const int* in_sizes, int n_in,
                              void* d_out, int out_size, void* d_ws, size_t ws_size,
                              hipStream_t stream) {
    const int*   x     = (const int*)d_in[0];
    const float* embed = (const float*)d_in[1];
    const float* Wi    = (const float*)d_in[2];
    const float* bi    = (const float*)d_in[3];
    const float* Wf    = (const float*)d_in[4];
    const float* bfv   = (const float*)d_in[5];
    const float* Wg    = (const float*)d_in[6];
    const float* bg    = (const float*)d_in[7];
    const float* Wo    = (const float*)d_in[8];
    const float* bo    = (const float*)d_in[9];
    const float* Wout  = (const float*)d_in[10];
    const float* bout  = (const float*)d_in[11];
    float* out = (float*)d_out;

    char* ws = (char*)d_ws;
    size_t off = 0;
    auto alloc = [&](size_t bytes) {
        void* p = ws + off;
        off = (off + bytes + 255) & ~(size_t)255;
        return p;
    };
    __hip_bfloat16* Wp   = (__hip_bfloat16*)alloc((size_t)4 * H_SZ * KTOT * 2);
    __hip_bfloat16* ebf  = (__hip_bfloat16*)alloc((size_t)T_SZ * B_SZ * KE * 2);
    __hip_bfloat16* hbuf = (__hip_bfloat16*)alloc((size_t)2 * B_SZ * H_SZ * 2);
    float* finh          = (float*)alloc((size_t)B_SZ * H_SZ * 4);
    int*   tcap          = (int*)alloc((size_t)B_SZ * 4);
    int*   cnt           = (int*)alloc((size_t)NRG * 4);
    (void)ws_size; (void)in_sizes; (void)n_in; (void)out_size;

    k_pack<<<832, 256, 0, stream>>>(Wi, Wf, Wg, Wo, Wp);
    k_gather<<<(T_SZ * B_SZ * (KE / 8) + 255) / 256, 256, 0, stream>>>(x, embed, ebf);
    k_misc<<<256, 256, 0, stream>>>(x, hbuf, finh, tcap, cnt);

    void* args[] = { &Wp, &ebf, &bi, &bfv, &bg, &bo, &hbuf, &finh, &tcap, &cnt };
    hipLaunchCooperativeKernel((void*)k_lstm, dim3(WGS), dim3(256), args, 0, stream);

    k_out<<<B_SZ, 64, 0, stream>>>(finh, Wout, bout, out);
}

// Round 2
// 1125.770 us; speedup vs baseline: 9.1034x; 9.1034x over previous
//
#include <hip/hip_runtime.h>
#include <hip/hip_bf16.h>
#include <stdint.h>

#define E_SZ 300
#define H_SZ 512
#define O_SZ 5
#define B_SZ 256
#define T_SZ 200
#define PAD_IDX 1

#define KH 512
#define KE 320            // padded e-width (300 -> 320)
#define KTOT 832          // 512 + 320
#define XS_W 812          // E + H, original weight row width
#define NK 26             // K-steps of 32 (16 h + 10 e)
#define NKH 16
#define NKE 10

#define NRG 8             // row groups (batch split) -> XCD-local with wg&7
#define ROWS 32           // batch rows per WG
#define NSPLIT 32         // n splits per row group
#define NW 16             // n columns per WG per gate
#define WGS 256
#define THREADS 512

#define HROW_PAD 520            // padded LDS row in bf16 elems (+8 -> 2-way-free)
#define HROW_B 1040             // bytes per padded row

typedef __bf16  bf16x8 __attribute__((ext_vector_type(8)));
typedef float   f32x4  __attribute__((ext_vector_type(4)));
typedef uint32_t u32x4 __attribute__((ext_vector_type(4)));

__device__ __forceinline__ float fsig(float x) { return 1.0f / (1.0f + __expf(-x)); }
__device__ __forceinline__ float ftanh_(float x) {
    float ax = fabsf(x);
    float e  = __expf(-2.0f * ax);
    float r  = (1.0f - e) / (1.0f + e);
    return x < 0.0f ? -r : r;
}

// ---------------- setup kernels ----------------

__global__ void k_pack(const float* __restrict__ Wi, const float* __restrict__ Wf,
                       const float* __restrict__ Wg, const float* __restrict__ Wo,
                       __hip_bfloat16* __restrict__ Wp) {
    int idx = blockIdx.x * blockDim.x + threadIdx.x;
    int total = 4 * H_SZ * KTOT;
    for (int i = idx; i < total; i += gridDim.x * blockDim.x) {
        int k  = i % KTOT;
        int gn = i / KTOT;
        int g = gn >> 9, n = gn & 511;
        const float* W = (g == 0) ? Wi : (g == 1) ? Wf : (g == 2) ? Wg : Wo;
        float v = 0.0f;
        if (k < KH) v = W[n * XS_W + k];
        else { int e = k - KH; if (e < E_SZ) v = W[n * XS_W + KH + e]; }
        Wp[(size_t)gn * KTOT + k] = __float2bfloat16(v);
    }
}

__global__ void k_gather(const int* __restrict__ x, const float* __restrict__ embed,
                         __hip_bfloat16* __restrict__ ebf) {
    int cid = blockIdx.x * blockDim.x + threadIdx.x;   // chunk of 8 elems
    const int nch = T_SZ * B_SZ * (KE / 8);
    if (cid >= nch) return;
    int ch = cid % (KE / 8);
    int tb = cid / (KE / 8);
    int b = tb % B_SZ;
    int t = tb / B_SZ;
    int row = x[b * T_SZ + t];
    const float* er = embed + (size_t)row * E_SZ;
    __hip_bfloat16 v[8];
    int e0 = ch * 8;
#pragma unroll
    for (int j = 0; j < 8; ++j) {
        int e = e0 + j;
        float f = (e < E_SZ) ? er[e] : 0.0f;
        v[j] = __float2bfloat16(f);
    }
    *reinterpret_cast<ulonglong2*>(ebf + ((size_t)t * B_SZ + b) * KE + e0) =
        *reinterpret_cast<const ulonglong2*>(v);
}

// zero final_h, zero (padded) counters, compute capture step per row
__global__ void k_misc(const int* __restrict__ x, float* __restrict__ final_h,
                       int* __restrict__ tcap, int* __restrict__ cnt) {
    int tid = blockIdx.x * blockDim.x + threadIdx.x;
    int n = gridDim.x * blockDim.x;
    for (int i = tid; i < B_SZ * H_SZ; i += n) final_h[i] = 0.0f;
    if (tid < NRG * 16) cnt[tid] = 0;
    if (tid < B_SZ) {
        int len = 0;
        for (int t = 0; t < T_SZ; ++t) len += (x[tid * T_SZ + t] != PAD_IDX);
        int tf = (len > 0) ? (len - 1) : 0;
        tcap[tid] = (x[tid * T_SZ + tf] == PAD_IDX) ? -1 : tf;
    }
}

// ---------------- recurrent cooperative kernel ----------------
// 256 WGs x 512 thr. WG (rg=wg&7, ns=wg>>3): rows rg*32..+31, cols ns*16..+15 x4 gates.
// Wave w: gate w&3, row-half w>>2. Weights in VGPRs; h staged via LDS; h-exchange
// via sc0/sc1 cache-bypass loads/stores (no fences); per-rowgroup fabric barrier.
__global__ void __launch_bounds__(THREADS, 2)
k_lstm(const __hip_bfloat16* __restrict__ Wp, const __hip_bfloat16* __restrict__ ebf,
       const float* __restrict__ bi, const float* __restrict__ bfv,
       const float* __restrict__ bg, const float* __restrict__ bo,
       __hip_bfloat16* __restrict__ hbuf, float* __restrict__ final_h,
       const int* __restrict__ tcap, int* __restrict__ cnt) {
    __shared__ __align__(16) __hip_bfloat16 h_lds[ROWS * HROW_PAD];  // 33,280 B
    __shared__ float pre_lds[4][ROWS][NW + 1];                       //  8,704 B

    const int wg   = blockIdx.x;
    const int rg   = wg & 7;
    const int ns   = wg >> 3;
    const int b0   = rg * ROWS;
    const int n0   = ns * NW;
    const int tid  = threadIdx.x;
    const int wave = tid >> 6;
    const int lane = tid & 63;
    const int l15  = lane & 15;
    const int l4   = lane >> 4;
    const int g    = wave & 3;   // gate
    const int rh   = wave >> 2;  // row half

    // zero h_lds (h0 = 0), including pads
    for (int i = tid; i < ROWS * HROW_PAD * 2 / 16; i += THREADS)
        reinterpret_cast<u32x4*>(h_lds)[i] = (u32x4){0u, 0u, 0u, 0u};

    // ---- weights -> registers (104 VGPRs/lane), once ----
    bf16x8 wreg[NK];
    {
        const __hip_bfloat16* wB =
            Wp + ((size_t)(g * H_SZ + n0 + l15)) * KTOT + l4 * 8;
#pragma unroll
        for (int kk = 0; kk < NK; ++kk)
            wreg[kk] = *reinterpret_cast<const bf16x8*>(wB + kk * 32);
    }

    // elementwise constants (threads 0..255: row er, col pair ec/ec+1)
    const int er  = tid >> 3;
    const int ec  = (tid & 7) * 2;
    const int enn = n0 + ec;
    const int ebb = b0 + er;
    float c0r = 0.f, c1r = 0.f;
    float bi0 = 0, bf0 = 0, bg0 = 0, bo0 = 0, bi1 = 0, bf1 = 0, bg1 = 0, bo1 = 0;
    int tc = -2;
    if (tid < 256) {
        bi0 = bi[enn];     bf0 = bfv[enn];     bg0 = bg[enn];     bo0 = bo[enn];
        bi1 = bi[enn + 1]; bf1 = bfv[enn + 1]; bg1 = bg[enn + 1]; bo1 = bo[enn + 1];
        tc = tcap[ebb];
    }

    const uint32_t lds_base  = (uint32_t)(uintptr_t)(&h_lds[0]);
    const uint32_t lds_stage = lds_base + wave * HROW_B + lane * 16;
    const char* hl_a = (const char*)(&h_lds[0]) + (rh * 16 + l15) * HROW_B + l4 * 16;
    const size_t BH = (size_t)B_SZ * H_SZ;

    __syncthreads();

#pragma unroll 1
    for (int t = 0; t < T_SZ; ++t) {
        f32x4 acc0 = {0.f, 0.f, 0.f, 0.f};
        f32x4 acc1 = {0.f, 0.f, 0.f, 0.f};
        u32x4 sg0, sg1, sg2, sg3;
        // 1. issue coherent staging loads of h[t-1] (rows b0+wave+8i, 1KB/wave/row)
        if (t > 0) {
            const char* gs = (const char*)(hbuf + (size_t)((t - 1) & 1) * BH +
                                           (size_t)(b0 + wave) * H_SZ) + lane * 16;
            asm volatile("global_load_dwordx4 %0, %1, off sc0 sc1"
                         : "=v"(sg0) : "v"((uint64_t)(uintptr_t)gs) : "memory");
            asm volatile("global_load_dwordx4 %0, %1, off sc0 sc1"
                         : "=v"(sg1) : "v"((uint64_t)(uintptr_t)(gs + 8 * H_SZ * 2)) : "memory");
            asm volatile("global_load_dwordx4 %0, %1, off sc0 sc1"
                         : "=v"(sg2) : "v"((uint64_t)(uintptr_t)(gs + 16 * H_SZ * 2)) : "memory");
            asm volatile("global_load_dwordx4 %0, %1, off sc0 sc1"
                         : "=v"(sg3) : "v"((uint64_t)(uintptr_t)(gs + 24 * H_SZ * 2)) : "memory");
        }
        // 2. e-part MFMAs (cached loads; hides staging latency)
        const __hip_bfloat16* ea =
            ebf + ((size_t)t * B_SZ + b0 + rh * 16 + l15) * KE + l4 * 8;
#pragma unroll
        for (int kk = 0; kk < NKE; ++kk) {
            bf16x8 a = *reinterpret_cast<const bf16x8*>(ea + kk * 32);
            if (kk & 1) acc1 = __builtin_amdgcn_mfma_f32_16x16x32_bf16(a, wreg[NKH + kk], acc1, 0, 0, 0);
            else        acc0 = __builtin_amdgcn_mfma_f32_16x16x32_bf16(a, wreg[NKH + kk], acc0, 0, 0, 0);
        }
        // 3. staged h -> LDS
        if (t > 0) {
            asm volatile("s_waitcnt vmcnt(0)\n\t"
                         "ds_write_b128 %0, %1\n\t"
                         "ds_write_b128 %0, %2 offset:8320\n\t"
                         "ds_write_b128 %0, %3 offset:16640\n\t"
                         "ds_write_b128 %0, %4 offset:24960\n\t"
                         "s_waitcnt lgkmcnt(0)"
                         :: "v"(lds_stage), "v"(sg0), "v"(sg1), "v"(sg2), "v"(sg3)
                         : "memory");
        }
        __syncthreads();
        // 4. h-part MFMAs from LDS (weights from registers)
#pragma unroll
        for (int kk = 0; kk < NKH; ++kk) {
            bf16x8 a = *reinterpret_cast<const bf16x8*>(hl_a + kk * 64);
            if (kk & 1) acc1 = __builtin_amdgcn_mfma_f32_16x16x32_bf16(a, wreg[kk], acc1, 0, 0, 0);
            else        acc0 = __builtin_amdgcn_mfma_f32_16x16x32_bf16(a, wreg[kk], acc0, 0, 0, 0);
        }
        f32x4 acc = acc0 + acc1;
        // 5. scatter pre-activations (C/D: row=(lane>>4)*4+j, col=lane&15)
#pragma unroll
        for (int j = 0; j < 4; ++j)
            pre_lds[g][rh * 16 + l4 * 4 + j][l15] = acc[j];
        __syncthreads();
        // 6. elementwise (threads 0..255, 2 cols each), coherent packed h store
        if (tid < 256) {
            float pi0 = pre_lds[0][er][ec]     + bi0;
            float pf_ = pre_lds[1][er][ec]     + bf0;
            float pg0 = pre_lds[2][er][ec]     + bg0;
            float po0 = pre_lds[3][er][ec]     + bo0;
            float pi1 = pre_lds[0][er][ec + 1] + bi1;
            float pf1 = pre_lds[1][er][ec + 1] + bf1;
            float pg1 = pre_lds[2][er][ec + 1] + bg1;
            float po1 = pre_lds[3][er][ec + 1] + bo1;
            float i0 = fsig(pi0), f0 = fsig(pf_), g0v = ftanh_(pg0), o0 = fsig(po0);
            float i1 = fsig(pi1), f1 = fsig(pf1), g1v = ftanh_(pg1), o1 = fsig(po1);
            c0r = f0 * c0r + i0 * g0v;
            c1r = f1 * c1r + i1 * g1v;
            float h0 = ftanh_(c0r) * o0;
            float h1 = ftanh_(c1r) * o1;
            uint32_t pk =
                (uint32_t)__builtin_bit_cast(uint16_t, __float2bfloat16(h0)) |
                ((uint32_t)__builtin_bit_cast(uint16_t, __float2bfloat16(h1)) << 16);
            char* hw = (char*)(hbuf + (size_t)(t & 1) * BH + (size_t)ebb * H_SZ + enn);
            asm volatile("global_store_dword %0, %1, off sc0 sc1"
                         :: "v"((uint64_t)(uintptr_t)hw), "v"(pk) : "memory");
            if (t == tc) {
                final_h[(size_t)ebb * H_SZ + enn]     = h0;
                final_h[(size_t)ebb * H_SZ + enn + 1] = h1;
            }
        }
        // 7. row-group barrier (no cache fences needed: h is cache-bypassed)
        if (t < T_SZ - 1) {
            asm volatile("s_waitcnt vmcnt(0)" ::: "memory");
            __syncthreads();
            if (tid == 0) {
                __hip_atomic_fetch_add(&cnt[rg * 16], 1, __ATOMIC_RELAXED,
                                       __HIP_MEMORY_SCOPE_AGENT);
                const int target = NSPLIT * (t + 1);
                while (__hip_atomic_load(&cnt[rg * 16], __ATOMIC_RELAXED,
                                         __HIP_MEMORY_SCOPE_AGENT) < target)
                    __builtin_amdgcn_s_sleep(1);
            }
            __syncthreads();
        }
    }
}

// ---------------- output head ----------------
__global__ void k_out(const float* __restrict__ fin, const float* __restrict__ Wout,
                      const float* __restrict__ bout, float* __restrict__ out) {
    int b = blockIdx.x;
    int lane = threadIdx.x;  // 64
    float s0 = 0, s1 = 0, s2 = 0, s3 = 0, s4 = 0;
    const float* fr = fin + (size_t)b * H_SZ;
    for (int n = lane; n < H_SZ; n += 64) {
        float h = fr[n];
        s0 += h * Wout[0 * H_SZ + n];
        s1 += h * Wout[1 * H_SZ + n];
        s2 += h * Wout[2 * H_SZ + n];
        s3 += h * Wout[3 * H_SZ + n];
        s4 += h * Wout[4 * H_SZ + n];
    }
#pragma unroll
    for (int off = 32; off >= 1; off >>= 1) {
        s0 += __shfl_down(s0, off);
        s1 += __shfl_down(s1, off);
        s2 += __shfl_down(s2, off);
        s3 += __shfl_down(s3, off);
        s4 += __shfl_down(s4, off);
    }
    if (lane == 0) {
        out[b * O_SZ + 0] = s0 + bout[0];
        out[b * O_SZ + 1] = s1 + bout[1];
        out[b * O_SZ + 2] = s2 + bout[2];
        out[b * O_SZ + 3] = s3 + bout[3];
        out[b * O_SZ + 4] = s4 + bout[4];
    }
}

// ---------------- launch ----------------
extern "C" void kernel_launch(void* const* d_in, const int* in_sizes, int n_in,
                              void* d_out, int out_size, void* d_ws, size_t ws_size,
                              hipStream_t stream) {
    const int*   x     = (const int*)d_in[0];
    const float* embed = (const float*)d_in[1];
    const float* Wi    = (const float*)d_in[2];
    const float* bi    = (const float*)d_in[3];
    const float* Wf    = (const float*)d_in[4];
    const float* bfv   = (const float*)d_in[5];
    const float* Wg    = (const float*)d_in[6];
    const float* bg    = (const float*)d_in[7];
    const float* Wo    = (const float*)d_in[8];
    const float* bo    = (const float*)d_in[9];
    const float* Wout  = (const float*)d_in[10];
    const float* bout  = (const float*)d_in[11];
    float* out = (float*)d_out;

    char* ws = (char*)d_ws;
    size_t off = 0;
    auto alloc = [&](size_t bytes) {
        void* p = ws + off;
        off = (off + bytes + 255) & ~(size_t)255;
        return p;
    };
    __hip_bfloat16* Wp   = (__hip_bfloat16*)alloc((size_t)4 * H_SZ * KTOT * 2);
    __hip_bfloat16* ebf  = (__hip_bfloat16*)alloc((size_t)T_SZ * B_SZ * KE * 2);
    __hip_bfloat16* hbuf = (__hip_bfloat16*)alloc((size_t)2 * B_SZ * H_SZ * 2);
    float* finh          = (float*)alloc((size_t)B_SZ * H_SZ * 4);
    int*   tcap          = (int*)alloc((size_t)B_SZ * 4);
    int*   cnt           = (int*)alloc((size_t)NRG * 16 * 4);
    (void)ws_size; (void)in_sizes; (void)n_in; (void)out_size;

    k_pack<<<832, 256, 0, stream>>>(Wi, Wf, Wg, Wo, Wp);
    k_gather<<<(T_SZ * B_SZ * (KE / 8) + 255) / 256, 256, 0, stream>>>(x, embed, ebf);
    k_misc<<<128, 256, 0, stream>>>(x, finh, tcap, cnt);

    void* args[] = { &Wp, &ebf, &bi, &bfv, &bg, &bo, &hbuf, &finh, &tcap, &cnt };
    hipLaunchCooperativeKernel((void*)k_lstm, dim3(WGS), dim3(THREADS), args, 0, stream);

    k_out<<<B_SZ, 64, 0, stream>>>(finh, Wout, bout, out);
}